// Round 8
// baseline (401.322 us; speedup 1.0000x reference)
//
#include <hip/hip_runtime.h>
#include <hip/hip_bf16.h>

// R-GCN layer (fp32 in/out): out = relu(agg0/deg0 @ W0 + agg1/deg1 @ W1 + x @ Wl + b)
// Round 8: agg MLP/occupancy push — 64-wide buckets (3125 blocks, 8KB LDS),
// 8-way unrolled gathers; bin chunk 8192 (391 blocks); convert/pack/zero fused.
//
// ws: wb ushort[12*8*64*8] | binned uint[2E] | xb bf16[N*128] |
//     aggb bf16[2N*128] | ghist int[NB] | S int[NB+1] | cursor int[NB]
// Requires N <= 131072 (src packed into 17 bits), 2N <= 204800 (NBMAX).

#define DFEAT 128
#define CHH 16384        // edges per hist block
#define CHB 8192         // edges per bin block
#define NBMAX 3200       // max buckets = ceil(2N/64)
#define CAP 1792         // LDS edge capacity per bucket (mean 1024, sd ~32)

typedef __attribute__((ext_vector_type(8))) short short8v;   // 8 bf16 (4 VGPRs)
typedef __attribute__((ext_vector_type(4))) float float4v;   // 4 fp32 acc

// Fused prep: [0,zb) zero ghist | [zb,zb+24) pack B | rest: convert x->bf16.
__global__ __launch_bounds__(256) void prep_kernel(
        const float4* __restrict__ x4, ushort4* __restrict__ xb4, int n4,
        const float* __restrict__ wrel, const float* __restrict__ wloop,
        unsigned short* __restrict__ wb,
        int* __restrict__ ghist, int NB, int zb) {
    int blk = blockIdx.x, tid = threadIdx.x;
    if (blk < zb) {
        int i = blk * 256 + tid;
        if (i < NB) ghist[i] = 0;
    } else if (blk < zb + 24) {
        int t = (blk - zb) * 256 + tid;   // 0..6143
        if (t < 12 * 8 * 64) {
            int lane = t & 63;
            int kbase = (t >> 9) * 32 + (lane >> 4) * 8;
            int col = (((t >> 6) & 7) << 4) + (lane & 15);
            unsigned short tmp[8];
#pragma unroll
            for (int j = 0; j < 8; ++j) {
                int k = kbase + j;
                float v = (k < 256) ? wrel[k * DFEAT + col]
                                    : wloop[(k - 256) * DFEAT + col];
                tmp[j] = __hip_bfloat16_raw(__float2bfloat16(v)).x;
            }
            *(ushort4*)(wb + t * 8)     = make_ushort4(tmp[0], tmp[1], tmp[2], tmp[3]);
            *(ushort4*)(wb + t * 8 + 4) = make_ushort4(tmp[4], tmp[5], tmp[6], tmp[7]);
        }
    } else {
        int i = (blk - zb - 24) * 256 + tid;
        if (i < n4) {
            float4 v = x4[i];
            ushort4 o;
            o.x = __hip_bfloat16_raw(__float2bfloat16(v.x)).x;
            o.y = __hip_bfloat16_raw(__float2bfloat16(v.y)).x;
            o.z = __hip_bfloat16_raw(__float2bfloat16(v.z)).x;
            o.w = __hip_bfloat16_raw(__float2bfloat16(v.w)).x;
            xb4[i] = o;
        }
    }
}

// Global bucket histogram (bucket = p>>6), LDS-privatized.
__global__ __launch_bounds__(256) void hist_kernel(
        const int* __restrict__ dst0, const int* __restrict__ dst1,
        int* __restrict__ ghist, int N, int E, int NB) {
    __shared__ int h[NBMAX];
    int tid = threadIdx.x;
    for (int i = tid; i < NBMAX; i += 256) h[i] = 0;
    __syncthreads();
    int lo = blockIdx.x * CHH, hi = min(2 * E, lo + CHH);
    for (int i = lo + tid; i < hi; i += 256) {
        int r = (i >= E) ? 1 : 0;
        int e = i - r * E;
        int t = r ? dst1[e] : dst0[e];
        atomicAdd(&h[(r * N + t) >> 6], 1);
    }
    __syncthreads();
    for (int b = tid; b < NB; b += 256) {
        int c = h[b];
        if (c) atomicAdd(&ghist[b], c);
    }
}

// Exclusive scan of ghist[n] -> S (+cursor copy); S[n] = total sentinel.
__global__ __launch_bounds__(256) void scan_kernel(const int* __restrict__ ghist,
                                                   int* __restrict__ S,
                                                   int* __restrict__ cursor,
                                                   int n, int total) {
    __shared__ int psum[256];
    int t = threadIdx.x;
    int cs = (n + 255) / 256;
    int s = 0;
    for (int j = 0; j < cs; ++j) {
        int idx = t * cs + j;
        if (idx < n) s += ghist[idx];
    }
    psum[t] = s; __syncthreads();
    for (int off = 1; off < 256; off <<= 1) {
        int add = (t >= off) ? psum[t - off] : 0;
        __syncthreads();
        psum[t] += add;
        __syncthreads();
    }
    int run = psum[t] - s;
    for (int j = 0; j < cs; ++j) {
        int idx = t * cs + j;
        if (idx < n) { S[idx] = run; cursor[idx] = run; run += ghist[idx]; }
    }
    if (t == 0) S[n] = total;
}

// Block-staged scatter: local hist -> bulk run reservation (1 global atomic
// per (block,bucket)) -> scatter into contiguous runs via LDS bump.
__global__ __launch_bounds__(256) void bin_kernel(
        const int* __restrict__ src0, const int* __restrict__ dst0,
        const int* __restrict__ src1, const int* __restrict__ dst1,
        int* __restrict__ cursor, unsigned* __restrict__ binned, int N, int E) {
    __shared__ int cnt[NBMAX];
    __shared__ int base[NBMAX];
    int tid = threadIdx.x;
    for (int i = tid; i < NBMAX; i += 256) cnt[i] = 0;
    __syncthreads();
    int lo = blockIdx.x * CHB, hi = min(2 * E, lo + CHB);
    for (int i = lo + tid; i < hi; i += 256) {
        int r = (i >= E) ? 1 : 0;
        int e = i - r * E;
        int t = r ? dst1[e] : dst0[e];
        atomicAdd(&cnt[(r * N + t) >> 6], 1);
    }
    __syncthreads();
    for (int b = tid; b < NBMAX; b += 256) {
        int c = cnt[b];
        if (c) base[b] = atomicAdd(&cursor[b], c);
    }
    __syncthreads();
    for (int i = lo + tid; i < hi; i += 256) {
        int r = (i >= E) ? 1 : 0;
        int e = i - r * E;
        int s = r ? src1[e] : src0[e];
        int t = r ? dst1[e] : dst0[e];
        int p = r * N + t;
        int slot = atomicAdd(&base[p >> 6], 1);
        binned[slot] = ((unsigned)(p & 63) << 17) | (unsigned)s;
    }
}

// One block per 64-p bucket. Local CSR in LDS (8KB), then one half-wave per
// p: register-accumulate in-edges via 8-way unrolled bf16 row gathers.
__global__ __launch_bounds__(256) void agg_kernel(
        const uint2* __restrict__ xb2,        // x bf16 rows as uint2[N][32]
        const unsigned* __restrict__ binned,
        const int* __restrict__ S,
        unsigned short* __restrict__ aggb, int M) {
    __shared__ unsigned ebuf[CAP];
    __shared__ int cnt[64], cur[64], rs[64], sh[64];
    int tid = threadIdx.x;
    int b = blockIdx.x;
    int estart = S[b], eend = S[b + 1];
    int total = eend - estart;
    int P0 = b << 6;
    int hw = tid >> 5, lane = tid & 31;

    if (total <= CAP) {
        if (tid < 64) cnt[tid] = 0;
        __syncthreads();
        for (int i = estart + tid; i < eend; i += 256)
            atomicAdd(&cnt[binned[i] >> 17], 1);
        __syncthreads();
        if (tid < 64) sh[tid] = cnt[tid];
        __syncthreads();
        for (int off = 1; off < 64; off <<= 1) {
            int add = (tid < 64 && tid >= off) ? sh[tid - off] : 0;
            __syncthreads();
            if (tid < 64) sh[tid] += add;
            __syncthreads();
        }
        if (tid < 64) { rs[tid] = sh[tid] - cnt[tid]; cur[tid] = sh[tid] - cnt[tid]; }
        __syncthreads();
        for (int i = estart + tid; i < eend; i += 256) {
            unsigned v = binned[i];
            int slot = atomicAdd(&cur[v >> 17], 1);
            ebuf[slot] = v;
        }
        __syncthreads();

        // Phase B: 8 half-waves x 8 p's, 8-way unrolled gathers.
#pragma unroll
        for (int pi = 0; pi < 8; ++pi) {
            int pl = hw * 8 + pi;
            int s0 = rs[pl], c = cnt[pl];
            float a0 = 0.f, a1 = 0.f, a2 = 0.f, a3 = 0.f;
            int e = 0;
            for (; e + 8 <= c; e += 8) {
                uint2 g[8];
#pragma unroll
                for (int j = 0; j < 8; ++j) {
                    int s = ebuf[s0 + e + j] & 0x1FFFF;
                    g[j] = xb2[(long long)s * 32 + lane];
                }
#pragma unroll
                for (int j = 0; j < 8; ++j) {
                    a0 += __uint_as_float(g[j].x << 16);
                    a1 += __uint_as_float(g[j].x & 0xffff0000u);
                    a2 += __uint_as_float(g[j].y << 16);
                    a3 += __uint_as_float(g[j].y & 0xffff0000u);
                }
            }
            for (; e < c; ++e) {
                int s = ebuf[s0 + e] & 0x1FFFF;
                uint2 g = xb2[(long long)s * 32 + lane];
                a0 += __uint_as_float(g.x << 16);
                a1 += __uint_as_float(g.x & 0xffff0000u);
                a2 += __uint_as_float(g.y << 16);
                a3 += __uint_as_float(g.y & 0xffff0000u);
            }
            int pg = P0 + pl;
            if (pg < M) {
                float inv = 1.0f / (float)max(c, 1);
                ushort4 w;
                w.x = __hip_bfloat16_raw(__float2bfloat16(a0 * inv)).x;
                w.y = __hip_bfloat16_raw(__float2bfloat16(a1 * inv)).x;
                w.z = __hip_bfloat16_raw(__float2bfloat16(a2 * inv)).x;
                w.w = __hip_bfloat16_raw(__float2bfloat16(a3 * inv)).x;
                *(ushort4*)(aggb + (long long)pg * DFEAT + 4 * lane) = w;
            }
        }
    } else {
        // Fallback (statistically unreachable): scan all bucket edges per p.
#pragma unroll
        for (int pi = 0; pi < 8; ++pi) {
            int pl = hw * 8 + pi;
            float a0 = 0.f, a1 = 0.f, a2 = 0.f, a3 = 0.f;
            int c = 0;
            for (int i = estart; i < eend; ++i) {
                unsigned v = binned[i];
                if ((int)(v >> 17) == pl) {
                    ++c;
                    uint2 g = xb2[(long long)(v & 0x1FFFF) * 32 + lane];
                    a0 += __uint_as_float(g.x << 16);
                    a1 += __uint_as_float(g.x & 0xffff0000u);
                    a2 += __uint_as_float(g.y << 16);
                    a3 += __uint_as_float(g.y & 0xffff0000u);
                }
            }
            int pg = P0 + pl;
            if (pg < M) {
                float inv = 1.0f / (float)max(c, 1);
                ushort4 w;
                w.x = __hip_bfloat16_raw(__float2bfloat16(a0 * inv)).x;
                w.y = __hip_bfloat16_raw(__float2bfloat16(a1 * inv)).x;
                w.z = __hip_bfloat16_raw(__float2bfloat16(a2 * inv)).x;
                w.w = __hip_bfloat16_raw(__float2bfloat16(a3 * inv)).x;
                *(ushort4*)(aggb + (long long)pg * DFEAT + 4 * lane) = w;
            }
        }
    }
}

// MFMA GEMM: out[row,col] = relu(sum_k A[row,k]*B[k,col] + bias[col]),
// A row = [aggb[row] | aggb[N+row] | xb[row]] (bf16), B pre-packed (wb).
__global__ __launch_bounds__(256) void mfma_gemm_kernel(
        const unsigned short* __restrict__ aggb,
        const unsigned short* __restrict__ xb,
        const unsigned short* __restrict__ wb,
        const float* __restrict__ bias,
        float* __restrict__ out, int N) {
    int tid = threadIdx.x;
    int wv = tid >> 6, lane = tid & 63;
    int R0 = blockIdx.x * 128 + wv * 32;
    int mrow = lane & 15, quad = lane >> 4;

    float4v acc[2][8];
#pragma unroll
    for (int rt = 0; rt < 2; ++rt)
#pragma unroll
        for (int ct = 0; ct < 8; ++ct) acc[rt][ct] = (float4v){0.f, 0.f, 0.f, 0.f};

    int n0 = min(R0 + mrow, N - 1);
    int n1 = min(R0 + 16 + mrow, N - 1);

#pragma unroll
    for (int kc = 0; kc < 12; ++kc) {
        int off = (kc & 3) * 32 + quad * 8;
        const unsigned short* s0;
        const unsigned short* s1;
        if (kc < 4)      { s0 = aggb + (size_t)n0 * DFEAT;       s1 = aggb + (size_t)n1 * DFEAT; }
        else if (kc < 8) { s0 = aggb + (size_t)(N + n0) * DFEAT; s1 = aggb + (size_t)(N + n1) * DFEAT; }
        else             { s0 = xb + (size_t)n0 * DFEAT;         s1 = xb + (size_t)n1 * DFEAT; }
        short8v a0 = *(const short8v*)(s0 + off);
        short8v a1 = *(const short8v*)(s1 + off);
#pragma unroll
        for (int ct = 0; ct < 8; ++ct) {
            short8v bfr = *(const short8v*)(wb + (((kc * 8 + ct) << 6) + lane) * 8);
            acc[0][ct] = __builtin_amdgcn_mfma_f32_16x16x32_bf16(a0, bfr, acc[0][ct], 0, 0, 0);
            acc[1][ct] = __builtin_amdgcn_mfma_f32_16x16x32_bf16(a1, bfr, acc[1][ct], 0, 0, 0);
        }
    }

#pragma unroll
    for (int ct = 0; ct < 8; ++ct) {
        int col = ct * 16 + mrow;
        float bv = bias[col];
#pragma unroll
        for (int rt = 0; rt < 2; ++rt) {
#pragma unroll
            for (int i = 0; i < 4; ++i) {
                int row = R0 + rt * 16 + quad * 4 + i;
                if (row < N)
                    out[(size_t)row * DFEAT + col] = fmaxf(acc[rt][ct][i] + bv, 0.f);
            }
        }
    }
}

extern "C" void kernel_launch(void* const* d_in, const int* in_sizes, int n_in,
                              void* d_out, int out_size, void* d_ws, size_t ws_size,
                              hipStream_t stream) {
    const float* x      = (const float*)d_in[0];
    const int* src_fwd  = (const int*)d_in[1];
    const int* dst_fwd  = (const int*)d_in[2];
    const int* src_bwd  = (const int*)d_in[3];
    const int* dst_bwd  = (const int*)d_in[4];
    const float* wrel   = (const float*)d_in[5];
    const float* wloop  = (const float*)d_in[6];
    const float* hbias  = (const float*)d_in[7];
    float* out          = (float*)d_out;

    int N = in_sizes[0] / DFEAT;
    int E = in_sizes[1];
    int M = 2 * N;
    int TE = 2 * E;
    int NB = (M + 63) / 64;          // 3125

    unsigned short* wb   = (unsigned short*)d_ws;                  // 96KB
    unsigned* binned     = (unsigned*)(wb + 12 * 8 * 64 * 8);      // [2E]
    unsigned short* xb   = (unsigned short*)(binned + (size_t)TE); // [N*128]
    unsigned short* aggb = xb + (size_t)N * DFEAT;                 // [2N*128]
    int* ghist           = (int*)(aggb + (size_t)M * DFEAT);       // [NB]
    int* S               = ghist + NB;                             // [NB+1]
    int* cursor          = S + NB + 1;                             // [NB]

    int n4 = N * (DFEAT / 4);
    int zb = (NB + 255) / 256;
    int prep_blocks = zb + 24 + (n4 + 255) / 256;
    prep_kernel<<<prep_blocks, 256, 0, stream>>>(
        (const float4*)x, (ushort4*)xb, n4, wrel, wloop, wb, ghist, NB, zb);

    int hblk = (TE + CHH - 1) / CHH;   // 196
    hist_kernel<<<hblk, 256, 0, stream>>>(dst_fwd, dst_bwd, ghist, N, E, NB);

    scan_kernel<<<1, 256, 0, stream>>>(ghist, S, cursor, NB, TE);

    int bblk = (TE + CHB - 1) / CHB;   // 391
    bin_kernel<<<bblk, 256, 0, stream>>>(
        src_fwd, dst_fwd, src_bwd, dst_bwd, cursor, binned, N, E);

    agg_kernel<<<NB, 256, 0, stream>>>((const uint2*)xb, binned, S, aggb, M);

    mfma_gemm_kernel<<<(N + 127) / 128, 256, 0, stream>>>(
        aggb, xb, wb, hbias, out, N);
}